// Round 12
// baseline (163.834 us; speedup 1.0000x reference)
//
#include <hip/hip_runtime.h>
#include <math.h>

#define CLASSES 8
#define SIZE 512
#define ISZ 512
#define CSZ 512
#define BATCH 64
#define CMS 4
#define NBUCKET 16
#define LR 0.01f
#define WCLIP 5.0f

// ---------------- kernel 1: pack ----------------
// Lt    (B, C*I)    : Lt[b*4096 + ci]                 = logits[ci, b]
// ctxT4 (D/4, B, 4) : ctxT4[(d>>2)*256 + 4*b + (d&3)] = context[b, d]
__global__ __launch_bounds__(256) void pack_pre(
    const float* __restrict__ logits,    // (C*I, B)
    const float* __restrict__ context,   // (B, D)
    float* __restrict__ Lt,
    float* __restrict__ ctxT4)
{
    __shared__ float t[64][65];
    const int bid  = blockIdx.x;
    const int lane = threadIdx.x & 63;
    const int w    = threadIdx.x >> 6;
    if (bid < 64) {
        const int r0 = bid << 6;                     // ci base
        #pragma unroll
        for (int rep = 0; rep < 16; ++rep) {
            int rr = w * 16 + rep;
            t[rr][lane] = logits[(size_t)(r0 + rr) * 64 + lane];
        }
        __syncthreads();
        const int ci = r0 + lane;
        #pragma unroll
        for (int rep = 0; rep < 16; ++rep) {
            int b = w * 16 + rep;
            Lt[(size_t)b * 4096 + ci] = t[lane][b];
        }
    } else {
        const int c0 = (bid - 64) << 6;              // d base
        #pragma unroll
        for (int rep = 0; rep < 16; ++rep) {
            int rr = w * 16 + rep;                   // b
            t[rr][lane] = context[(size_t)rr * 512 + c0 + lane];
        }
        __syncthreads();
        #pragma unroll
        for (int rep = 0; rep < 16; ++rep) {
            int dd = c0 + w * 16 + rep;              // d
            ctxT4[(size_t)(dd >> 2) * 256 + 4 * lane + (dd & 3)] = t[lane][w * 16 + rep];
        }
    }
}

// ---------------- kernel 2: distances -> bucket idx (R8/R11 verbatim) ----------------
// Proven passing + fast. Rules (R1/R3/R10 blowups): cm operand WAVE-UNIFORM
// (readfirstlane -> s_load path); ctx operand LANE-CONSECUTIVE (lane=b, 16B
// stride -> coalesced). Single-acc 4-term chain, unroll 4.
// Do NOT re-derive this loop (R5/R6 knife-edge post-mortem).
__global__ __launch_bounds__(256, 8) void dist_kernel(
    const float* __restrict__ cmaps,     // (C, S, 4, 512)
    const float* __restrict__ cbias,     // (C, S, 4, 1)
    const float* __restrict__ ctxT4,     // packed context
    unsigned char* __restrict__ idxOut)  // (4096, 64)
{
    __shared__ int bits[CMS * BATCH];

    const int tid  = threadIdx.x;
    const int cs   = blockIdx.x;       // c*SIZE + s
    const int lane = tid & 63;
    const int wv   = tid >> 6;
    const int k    = __builtin_amdgcn_readfirstlane(wv);   // wave-uniform

    const float4* cmg = (const float4*)(cmaps + ((size_t)cs * CMS + k) * CSZ);
    {
        const float4* ct4 = (const float4*)ctxT4 + lane;
        float acc = 0.f;
        #pragma unroll 4
        for (int d4 = 0; d4 < 128; ++d4) {
            float4 cm4 = cmg[d4];                    // uniform -> s_load_dwordx4
            float4 cv  = ct4[(size_t)d4 * 64];
            acc += cm4.x * cv.x + cm4.y * cv.y + cm4.z * cv.z + cm4.w * cv.w;
        }
        float bias = cbias[(size_t)cs * CMS + k];
        bits[k * BATCH + lane] = (acc > bias) ? 1 : 0;
    }
    __syncthreads();

    if (wv == 0) {
        int idx_b = bits[lane] | (bits[BATCH + lane] << 1) |
                    (bits[2 * BATCH + lane] << 2) | (bits[3 * BATCH + lane] << 3);
        idxOut[(size_t)cs * BATCH + lane] = (unsigned char)idx_b;
    }
}

// ---------------- kernel 3: barrier-free wave-per-cs gather-dot + update ----------------
// Bucket-major wave-uniform iteration: ballot mask per bucket r (SGPR), W[r]
// loaded coalesced (2 f4/lane), per-b dot via butterfly shfl_xor all-reduce.
// Zero LDS, zero syncthreads, 8 blocks/CU. out/update FP order changes are
// within tolerance (no downstream comparisons).
__global__ __launch_bounds__(256, 8) void gln_bc2(
    const float* __restrict__ target,   // (C, B)
    const float* __restrict__ weights,  // (C, S, 16, 512)
    const unsigned char* __restrict__ idxIn,
    const float* __restrict__ Lt,       // (B, C*I)
    float* __restrict__ out,            // (C, S, B)
    float* __restrict__ outW)           // (C, S, 16, 512)
{
    const int tid  = threadIdx.x;
    const int lane = tid & 63;
    const int wv   = tid >> 6;
    const int cs   = blockIdx.x * 4 + wv;
    const int c    = cs >> 9;

    const float4* gW = (const float4*)(weights + (size_t)cs * (NBUCKET * ISZ)); // 2048 f4
    const int idx_b = idxIn[(size_t)cs * BATCH + lane];

    float out_acc = 0.f;
    unsigned long long m0, m1, m2, m3, m4, m5, m6, m7,
                       m8, m9, m10, m11, m12, m13, m14, m15;

#define DO_BUCKET(R, MR)                                                        \
    {                                                                           \
        MR = __ballot(idx_b == R);                                              \
        unsigned long long m = MR;                                              \
        if (m) {                                                                \
            float4 w0 = gW[R * 128 + lane];                                     \
            float4 w1 = gW[R * 128 + 64 + lane];                                \
            while (m) {                                                         \
                int b = __ffsll((unsigned long long)m) - 1;                     \
                m &= m - 1;                                                     \
                const float4* Lb = (const float4*)(Lt + (size_t)b * 4096 + c * 512); \
                float4 l0 = Lb[lane];                                           \
                float4 l1 = Lb[64 + lane];                                      \
                float p = w0.x * l0.x + w0.y * l0.y + w0.z * l0.z + w0.w * l0.w \
                        + w1.x * l1.x + w1.y * l1.y + w1.z * l1.z + w1.w * l1.w;\
                p += __shfl_xor(p, 1);  p += __shfl_xor(p, 2);                  \
                p += __shfl_xor(p, 4);  p += __shfl_xor(p, 8);                  \
                p += __shfl_xor(p, 16); p += __shfl_xor(p, 32);                 \
                if (lane == b) out_acc = p;                                     \
            }                                                                   \
        }                                                                       \
    }
    DO_BUCKET(0, m0)   DO_BUCKET(1, m1)   DO_BUCKET(2, m2)   DO_BUCKET(3, m3)
    DO_BUCKET(4, m4)   DO_BUCKET(5, m5)   DO_BUCKET(6, m6)   DO_BUCKET(7, m7)
    DO_BUCKET(8, m8)   DO_BUCKET(9, m9)   DO_BUCKET(10, m10) DO_BUCKET(11, m11)
    DO_BUCKET(12, m12) DO_BUCKET(13, m13) DO_BUCKET(14, m14) DO_BUCKET(15, m15)
#undef DO_BUCKET

    // out + diff (per-lane, no LDS)
    const float hi = 4.595119850134589f;    // logit(0.99)
    float oc = fminf(fmaxf(out_acc, -hi), hi);
    out[(size_t)cs * BATCH + lane] = oc;
    float sig = 1.f / (1.f + expf(-oc));
    float diff = LR * (sig - target[c * BATCH + lane]);

    // update: per bucket, last-writer b = 63-clz(mask); W re-read is L1/L2-hot
    float4* gO = (float4*)(outW + (size_t)cs * (NBUCKET * ISZ));

#define UPD_BUCKET(R, MR)                                                       \
    {                                                                           \
        float4 w0 = gW[R * 128 + lane];                                         \
        float4 w1 = gW[R * 128 + 64 + lane];                                    \
        float4 r0 = w0, r1 = w1;                                                \
        if (MR) {                                                               \
            int bl = 63 - __clzll(MR);                                          \
            float coef = __shfl(diff, bl);                                      \
            const float4* Lb = (const float4*)(Lt + (size_t)bl * 4096 + c * 512); \
            float4 l0 = Lb[lane];                                               \
            float4 l1 = Lb[64 + lane];                                          \
            r0.x = fminf(fmaxf(w0.x - coef * l0.x, -WCLIP), WCLIP);             \
            r0.y = fminf(fmaxf(w0.y - coef * l0.y, -WCLIP), WCLIP);             \
            r0.z = fminf(fmaxf(w0.z - coef * l0.z, -WCLIP), WCLIP);             \
            r0.w = fminf(fmaxf(w0.w - coef * l0.w, -WCLIP), WCLIP);             \
            r1.x = fminf(fmaxf(w1.x - coef * l1.x, -WCLIP), WCLIP);             \
            r1.y = fminf(fmaxf(w1.y - coef * l1.y, -WCLIP), WCLIP);             \
            r1.z = fminf(fmaxf(w1.z - coef * l1.z, -WCLIP), WCLIP);             \
            r1.w = fminf(fmaxf(w1.w - coef * l1.w, -WCLIP), WCLIP);             \
        }                                                                       \
        gO[R * 128 + lane] = r0;                                                \
        gO[R * 128 + 64 + lane] = r1;                                           \
    }
    UPD_BUCKET(0, m0)   UPD_BUCKET(1, m1)   UPD_BUCKET(2, m2)   UPD_BUCKET(3, m3)
    UPD_BUCKET(4, m4)   UPD_BUCKET(5, m5)   UPD_BUCKET(6, m6)   UPD_BUCKET(7, m7)
    UPD_BUCKET(8, m8)   UPD_BUCKET(9, m9)   UPD_BUCKET(10, m10) UPD_BUCKET(11, m11)
    UPD_BUCKET(12, m12) UPD_BUCKET(13, m13) UPD_BUCKET(14, m14) UPD_BUCKET(15, m15)
#undef UPD_BUCKET
}

extern "C" void kernel_launch(void* const* d_in, const int* in_sizes, int n_in,
                              void* d_out, int out_size, void* d_ws, size_t ws_size,
                              hipStream_t stream) {
    const float* logits  = (const float*)d_in[0];  // (8,512,64)
    const float* context = (const float*)d_in[1];  // (64,512)
    const float* target  = (const float*)d_in[2];  // (8,64)
    const float* cmaps   = (const float*)d_in[3];  // (8,512,4,512)
    const float* cbias   = (const float*)d_in[4];  // (8,512,4,1)
    const float* weights = (const float*)d_in[5];  // (8,512,16,512)

    float* out  = (float*)d_out;                        // (8,512,64)
    float* outW = out + (size_t)CLASSES * SIZE * BATCH; // (8,512,16,512)

    float* Lt    = (float*)d_ws;            // 1 MB
    float* ctxT4 = Lt + 262144;             // 128 KB
    unsigned char* idxb = (unsigned char*)(ctxT4 + 32768);   // 256 KB

    pack_pre<<<72, 256, 0, stream>>>(logits, context, Lt, ctxT4);
    dist_kernel<<<CLASSES * SIZE, 256, 0, stream>>>(cmaps, cbias, ctxT4, idxb);
    gln_bc2<<<CLASSES * SIZE / 4, 256, 0, stream>>>(target, weights, idxb, Lt, out, outW);
}

// Round 13
// 157.517 us; speedup vs baseline: 1.0401x; 1.0401x over previous
//
#include <hip/hip_runtime.h>
#include <math.h>

#define CLASSES 8
#define SIZE 512
#define ISZ 512
#define CSZ 512
#define BATCH 64
#define CMS 4
#define NBUCKET 16
#define LR 0.01f
#define WCLIP 5.0f
#define HSTRIDE 260    // half-tile row stride (floats): rows at banks 4r%32 -> 2-way max (free)

// ---------------- kernel 1: pack (R4/R11 verbatim) ----------------
// Lt    (B, C*I)      : Lt[b*4096 + ci]                  = logits[ci, b]
// Lpk   (C*I/4, B, 4) : Lpk[(ci>>2)*256 + 4*b + (ci&3)]  = logits[ci, b]
// ctxT4 (D/4, B, 4)   : ctxT4[(d>>2)*256 + 4*b + (d&3)]  = context[b, d]
__global__ __launch_bounds__(256) void pack_pre(
    const float* __restrict__ logits,    // (C*I, B)
    const float* __restrict__ context,   // (B, D)
    float* __restrict__ Lt,
    float* __restrict__ Lpk,
    float* __restrict__ ctxT4)
{
    __shared__ float t[64][65];
    const int bid  = blockIdx.x;
    const int lane = threadIdx.x & 63;
    const int w    = threadIdx.x >> 6;
    if (bid < 64) {
        const int r0 = bid << 6;                     // ci base
        #pragma unroll
        for (int rep = 0; rep < 16; ++rep) {
            int rr = w * 16 + rep;
            t[rr][lane] = logits[(size_t)(r0 + rr) * 64 + lane];
        }
        __syncthreads();
        const int ci = r0 + lane;
        #pragma unroll
        for (int rep = 0; rep < 16; ++rep) {
            int b = w * 16 + rep;
            float v = t[lane][b];
            Lt[(size_t)b * 4096 + ci] = v;
            Lpk[(size_t)(ci >> 2) * 256 + 4 * b + (ci & 3)] = v;
        }
    } else {
        const int c0 = (bid - 64) << 6;              // d base
        #pragma unroll
        for (int rep = 0; rep < 16; ++rep) {
            int rr = w * 16 + rep;                   // b
            t[rr][lane] = context[(size_t)rr * 512 + c0 + lane];
        }
        __syncthreads();
        #pragma unroll
        for (int rep = 0; rep < 16; ++rep) {
            int dd = c0 + w * 16 + rep;              // d
            ctxT4[(size_t)(dd >> 2) * 256 + 4 * lane + (dd & 3)] = t[lane][w * 16 + rep];
        }
    }
}

// ---------------- kernel 2: distances -> bucket idx (R8/R11 verbatim) ----------------
// Proven passing + fast. Rules (R1/R3/R10 blowups): cm operand WAVE-UNIFORM
// (readfirstlane -> s_load path); ctx operand LANE-CONSECUTIVE (lane=b, 16B
// stride -> coalesced). Single-acc 4-term chain, unroll 4.
// Do NOT re-derive this loop (R5/R6 knife-edge post-mortem).
__global__ __launch_bounds__(256, 8) void dist_kernel(
    const float* __restrict__ cmaps,     // (C, S, 4, 512)
    const float* __restrict__ cbias,     // (C, S, 4, 1)
    const float* __restrict__ ctxT4,     // packed context
    unsigned char* __restrict__ idxOut)  // (4096, 64)
{
    __shared__ int bits[CMS * BATCH];

    const int tid  = threadIdx.x;
    const int cs   = blockIdx.x;       // c*SIZE + s
    const int lane = tid & 63;
    const int wv   = tid >> 6;
    const int k    = __builtin_amdgcn_readfirstlane(wv);   // wave-uniform

    const float4* cmg = (const float4*)(cmaps + ((size_t)cs * CMS + k) * CSZ);
    {
        const float4* ct4 = (const float4*)ctxT4 + lane;
        float acc = 0.f;
        #pragma unroll 4
        for (int d4 = 0; d4 < 128; ++d4) {
            float4 cm4 = cmg[d4];                    // uniform -> s_load_dwordx4
            float4 cv  = ct4[(size_t)d4 * 64];
            acc += cm4.x * cv.x + cm4.y * cv.y + cm4.z * cv.z + cm4.w * cv.w;
        }
        float bias = cbias[(size_t)cs * CMS + k];
        bits[k * BATCH + lane] = (acc > bias) ? 1 : 0;
    }
    __syncthreads();

    if (wv == 0) {
        int idx_b = bits[lane] | (bits[BATCH + lane] << 1) |
                    (bits[2 * BATCH + lane] << 2) | (bits[3 * BATCH + lane] << 3);
        idxOut[(size_t)cs * BATCH + lane] = (unsigned char)idx_b;
    }
}

// ---------------- kernel 3: gather-dot + update, half-I LDS tile ----------------
// 16x260 f32 tile (16.6 KB) staged from wreg by wave parity -> 17.9 KB LDS total
// -> 8 blocks/CU target. Gather in 2 halves summed into one acc (out reorder is
// safe: no downstream comparisons). Normal stores (nt inflated WRITE, R11).
__global__ __launch_bounds__(256, 8) void gln_bc(
    const float* __restrict__ target,   // (C, B)
    const float* __restrict__ weights,  // (C, S, 16, 512)
    const unsigned char* __restrict__ idxIn,
    const float* __restrict__ Lt,       // (B, C*I)
    const float* __restrict__ Lpk,      // (C*I/4, B, 4)
    float* __restrict__ out,            // (C, S, B)
    float* __restrict__ outW)           // (C, S, 16, 512)
{
    __shared__ float Wl[NBUCKET * HSTRIDE];   // 16.6 KB half tile
    __shared__ float partial[4 * BATCH];
    __shared__ float diff_l[BATCH];

    const int tid  = threadIdx.x;
    const int cs   = blockIdx.x;
    const int c    = cs >> 9;
    const int lane = tid & 63;
    const int wv   = tid >> 6;

    // W slice (16 x 512 f32) -> regs, coalesced; wreg[it] = f4 #(tid + it*256)
    // i.e. row = 2*it + (tid>>7), col4 = tid&127 (col fixed per thread).
    float4 wreg[8];
    const float4* gW = (const float4*)(weights + (size_t)cs * (NBUCKET * ISZ));
    #pragma unroll
    for (int it = 0; it < 8; ++it) wreg[it] = gW[tid + it * 256];

    const int idx_b = idxIn[(size_t)cs * BATCH + lane];

    // all 16 last-writers in registers (wave-redundant ballots, no LDS/barrier)
    int blast_r[16];
    #pragma unroll
    for (int j = 0; j < NBUCKET; ++j) {
        unsigned long long m = __ballot(idx_b == j);
        blast_r[j] = m ? (63 - __clzll(m)) : -1;    // np last-write-wins
    }

    // gather-dot over two I-halves; threads with (tid&127)<64 hold half-0 cols,
    // >=64 hold half-1 cols -> wave parity (wv&1)==h stages half h from wreg.
    const int col   = tid & 63;
    const int myrow = tid >> 7;                      // 0 or 1
    const int stage_par = (tid >> 6) & 1;            // waves 0,2 -> 0; 1,3 -> 1
    float acc = 0.f;
    const float4* Lp4 = (const float4*)Lpk;
    #pragma unroll
    for (int h = 0; h < 2; ++h) {
        if (stage_par == h) {
            #pragma unroll
            for (int it = 0; it < 8; ++it) {
                int row = 2 * it + myrow;
                *(float4*)&Wl[row * HSTRIDE + col * 4] = wreg[it];
            }
        }
        __syncthreads();
        const int base4 = (c * 128 + h * 64 + wv * 16) * 64 + lane;
        const int wb    = idx_b * HSTRIDE + wv * 64;
        #pragma unroll 4
        for (int d4 = 0; d4 < 16; ++d4) {
            float4 w4 = *(const float4*)&Wl[wb + d4 * 4];
            float4 l4 = Lp4[(size_t)base4 + d4 * 64];
            acc += w4.x * l4.x + w4.y * l4.y + w4.z * l4.z + w4.w * l4.w;
        }
        __syncthreads();
    }
    partial[wv * BATCH + lane] = acc;
    __syncthreads();

    // wave 0: out + diff
    if (wv == 0) {
        float s = partial[lane] + partial[BATCH + lane] +
                  partial[2 * BATCH + lane] + partial[3 * BATCH + lane];
        const float hi = 4.595119850134589f;    // logit(0.99)
        float oc = fminf(fmaxf(s, -hi), hi);
        out[(size_t)cs * BATCH + lane] = oc;
        float sig = 1.f / (1.f + expf(-oc));
        diff_l[lane] = LR * (sig - target[c * BATCH + lane]);
    }
    __syncthreads();

    // update from wreg; Lt loads are L2-hot, hidden by 2x occupancy
    float* gO = outW + (size_t)cs * (NBUCKET * ISZ);
    const float* LtC = Lt + (size_t)c * ISZ;
    const int col4 = tid & 127;
    const int hi_half = (tid >> 7) & 1;
    #pragma unroll
    for (int it = 0; it < 8; ++it) {
        int f  = tid + it * 256;
        int bl = hi_half ? blast_r[2 * it + 1] : blast_r[2 * it];
        float4 w4 = wreg[it];
        float4 r = w4;
        if (bl >= 0) {
            float coef = diff_l[bl];
            float4 l4  = ((const float4*)(LtC + (size_t)bl * 4096))[col4];
            r.x = fminf(fmaxf(w4.x - coef * l4.x, -WCLIP), WCLIP);
            r.y = fminf(fmaxf(w4.y - coef * l4.y, -WCLIP), WCLIP);
            r.z = fminf(fmaxf(w4.z - coef * l4.z, -WCLIP), WCLIP);
            r.w = fminf(fmaxf(w4.w - coef * l4.w, -WCLIP), WCLIP);
        }
        ((float4*)gO)[f] = r;
    }
}

extern "C" void kernel_launch(void* const* d_in, const int* in_sizes, int n_in,
                              void* d_out, int out_size, void* d_ws, size_t ws_size,
                              hipStream_t stream) {
    const float* logits  = (const float*)d_in[0];  // (8,512,64)
    const float* context = (const float*)d_in[1];  // (64,512)
    const float* target  = (const float*)d_in[2];  // (8,64)
    const float* cmaps   = (const float*)d_in[3];  // (8,512,4,512)
    const float* cbias   = (const float*)d_in[4];  // (8,512,4,1)
    const float* weights = (const float*)d_in[5];  // (8,512,16,512)

    float* out  = (float*)d_out;                        // (8,512,64)
    float* outW = out + (size_t)CLASSES * SIZE * BATCH; // (8,512,16,512)

    float* Lt    = (float*)d_ws;            // 1 MB
    float* Lpk   = Lt + 262144;             // 1 MB
    float* ctxT4 = Lpk + 262144;            // 128 KB
    unsigned char* idxb = (unsigned char*)(ctxT4 + 32768);   // 256 KB

    pack_pre<<<72, 256, 0, stream>>>(logits, context, Lt, Lpk, ctxT4);
    dist_kernel<<<CLASSES * SIZE, 256, 0, stream>>>(cmaps, cbias, ctxT4, idxb);
    gln_bc<<<CLASSES * SIZE, 256, 0, stream>>>(target, weights, idxb, Lt, Lpk, out, outW);
}

// Round 14
// 156.432 us; speedup vs baseline: 1.0473x; 1.0069x over previous
//
#include <hip/hip_runtime.h>
#include <math.h>

#define CLASSES 8
#define SIZE 512
#define ISZ 512
#define CSZ 512
#define BATCH 64
#define CMS 4
#define NBUCKET 16
#define LR 0.01f
#define WCLIP 5.0f
#define WSTRIDE 516    // W gather: banks 4*(idx+off)%32 -> worst 2-way (free)

// ---------------- kernel 1: pack (R4/R11 verbatim) ----------------
// Lt    (B, C*I)      : Lt[b*4096 + ci]                  = logits[ci, b]
// Lpk   (C*I/4, B, 4) : Lpk[(ci>>2)*256 + 4*b + (ci&3)]  = logits[ci, b]
// ctxT4 (D/4, B, 4)   : ctxT4[(d>>2)*256 + 4*b + (d&3)]  = context[b, d]
__global__ __launch_bounds__(256) void pack_pre(
    const float* __restrict__ logits,    // (C*I, B)
    const float* __restrict__ context,   // (B, D)
    float* __restrict__ Lt,
    float* __restrict__ Lpk,
    float* __restrict__ ctxT4)
{
    __shared__ float t[64][65];
    const int bid  = blockIdx.x;
    const int lane = threadIdx.x & 63;
    const int w    = threadIdx.x >> 6;
    if (bid < 64) {
        const int r0 = bid << 6;                     // ci base
        #pragma unroll
        for (int rep = 0; rep < 16; ++rep) {
            int rr = w * 16 + rep;
            t[rr][lane] = logits[(size_t)(r0 + rr) * 64 + lane];
        }
        __syncthreads();
        const int ci = r0 + lane;
        #pragma unroll
        for (int rep = 0; rep < 16; ++rep) {
            int b = w * 16 + rep;
            float v = t[lane][b];
            Lt[(size_t)b * 4096 + ci] = v;
            Lpk[(size_t)(ci >> 2) * 256 + 4 * b + (ci & 3)] = v;
        }
    } else {
        const int c0 = (bid - 64) << 6;              // d base
        #pragma unroll
        for (int rep = 0; rep < 16; ++rep) {
            int rr = w * 16 + rep;                   // b
            t[rr][lane] = context[(size_t)rr * 512 + c0 + lane];
        }
        __syncthreads();
        #pragma unroll
        for (int rep = 0; rep < 16; ++rep) {
            int dd = c0 + w * 16 + rep;              // d
            ctxT4[(size_t)(dd >> 2) * 256 + 4 * lane + (dd & 3)] = t[lane][w * 16 + rep];
        }
    }
}

// ---------------- kernel 2: distances -> bucket idx ----------------
// 4 cs per block (grid 1024): amortizes each wave's 128 KB ctx stream over
// 4 cs (L1 traffic/cs drops 4x). Inner d4 loop is the FROZEN R8/R11 body,
// compiled once (#pragma unroll 1 on the cs loop -> single-acc chain, no
// cross-cs interleaving). Rules: cm operand WAVE-UNIFORM (s_load path);
// ctx operand LANE-CONSECUTIVE. Do NOT re-derive (R5/R6 knife-edge).
__global__ __launch_bounds__(256, 8) void dist_kernel(
    const float* __restrict__ cmaps,     // (C, S, 4, 512)
    const float* __restrict__ cbias,     // (C, S, 4, 1)
    const float* __restrict__ ctxT4,     // packed context
    unsigned char* __restrict__ idxOut)  // (4096, 64)
{
    __shared__ int bits[4][CMS * BATCH];

    const int tid  = threadIdx.x;
    const int lane = tid & 63;
    const int wv   = tid >> 6;
    const int k    = __builtin_amdgcn_readfirstlane(wv);   // wave-uniform
    const int cs0  = blockIdx.x * 4;

    const float4* ct4 = (const float4*)ctxT4 + lane;
    #pragma unroll 1
    for (int i = 0; i < 4; ++i) {
        const int cs = cs0 + i;
        const float4* cmg = (const float4*)(cmaps + ((size_t)cs * CMS + k) * CSZ);
        float acc = 0.f;
        #pragma unroll 4
        for (int d4 = 0; d4 < 128; ++d4) {
            float4 cm4 = cmg[d4];                    // uniform -> s_load_dwordx4
            float4 cv  = ct4[(size_t)d4 * 64];
            acc += cm4.x * cv.x + cm4.y * cv.y + cm4.z * cv.z + cm4.w * cv.w;
        }
        float bias = cbias[(size_t)cs * CMS + k];
        bits[i][k * BATCH + lane] = (acc > bias) ? 1 : 0;
    }
    __syncthreads();

    {   // wave wv combines cs0+wv
        int idx_b = bits[wv][lane] | (bits[wv][BATCH + lane] << 1) |
                    (bits[wv][2 * BATCH + lane] << 2) | (bits[wv][3 * BATCH + lane] << 3);
        idxOut[(size_t)(cs0 + wv) * BATCH + lane] = (unsigned char)idx_b;
    }
}

// ---------------- kernel 3: gather-dot + update (R11 verbatim, normal store) ----------------
__global__ __launch_bounds__(256, 4) void gln_bc(
    const float* __restrict__ target,   // (C, B)
    const float* __restrict__ weights,  // (C, S, 16, 512)
    const unsigned char* __restrict__ idxIn,
    const float* __restrict__ Lt,
    const float* __restrict__ Lpk,
    float* __restrict__ out,            // (C, S, B)
    float* __restrict__ outW)           // (C, S, 16, 512)
{
    __shared__ float Wl[NBUCKET * WSTRIDE];   // 33 KB padded rows
    __shared__ float partial[4 * BATCH];
    __shared__ float diff_l[BATCH];

    const int tid  = threadIdx.x;
    const int cs   = blockIdx.x;
    const int c    = cs >> 9;
    const int lane = tid & 63;
    const int wv   = tid >> 6;

    // stage W slice (16 x 512 f32): global -> regs
    float4 wreg[8];
    const float4* gW = (const float4*)(weights + (size_t)cs * (NBUCKET * ISZ));
    #pragma unroll
    for (int it = 0; it < 8; ++it) wreg[it] = gW[tid + it * 256];

    const int idx_b = idxIn[(size_t)cs * BATCH + lane];

    // all 16 last-writers in registers (wave-redundant ballots, no LDS/barrier)
    int blast_r[16];
    #pragma unroll
    for (int j = 0; j < NBUCKET; ++j) {
        unsigned long long m = __ballot(idx_b == j);
        blast_r[j] = m ? (63 - __clzll(m)) : -1;    // np last-write-wins
    }

    // prefetch phase-3 Lt operands (row = (tid>>7) + 2*it, col4 = tid&127);
    // static reg indexing only (runtime-indexed arrays spill to scratch)
    const float* LtC = Lt + (size_t)c * ISZ;
    const int col4 = tid & 127;
    const int hi_half = (tid >> 7) & 1;
    float4 lreg[8];
    int    blv[8];
    #pragma unroll
    for (int it = 0; it < 8; ++it) {
        int bl = hi_half ? blast_r[2 * it + 1] : blast_r[2 * it];
        blv[it] = bl;
        int blc = (bl >= 0) ? bl : 0;
        lreg[it] = ((const float4*)(LtC + (size_t)blc * 4096))[col4];
    }

    // stage W to padded LDS for the gather
    #pragma unroll
    for (int it = 0; it < 8; ++it) {
        int f = tid + it * 256;
        *(float4*)&Wl[(f >> 7) * WSTRIDE + (f & 127) * 4] = wreg[it];
    }
    __syncthreads();

    // gather-dot: wave wv covers i in [128*wv, 128*wv+128)
    {
        const float4* Lp4 = (const float4*)Lpk;
        const int base4 = (c * 128 + wv * 32) * 64 + lane;
        const int wb    = idx_b * WSTRIDE + wv * 128;
        float acc = 0.f;
        #pragma unroll 4
        for (int d4 = 0; d4 < 32; ++d4) {
            float4 w4 = *(const float4*)&Wl[wb + d4 * 4];
            float4 l4 = Lp4[(size_t)base4 + d4 * 64];
            acc += w4.x * l4.x + w4.y * l4.y + w4.z * l4.z + w4.w * l4.w;
        }
        partial[wv * BATCH + lane] = acc;
    }
    __syncthreads();

    // wave 0: out + diff
    if (wv == 0) {
        float s = partial[lane] + partial[BATCH + lane] +
                  partial[2 * BATCH + lane] + partial[3 * BATCH + lane];
        const float hi = 4.595119850134589f;    // logit(0.99)
        float oc = fminf(fmaxf(s, -hi), hi);
        out[(size_t)cs * BATCH + lane] = oc;
        float sig = 1.f / (1.f + expf(-oc));
        diff_l[lane] = LR * (sig - target[c * BATCH + lane]);
    }
    __syncthreads();

    // phase 3: update from regs, normal stores (nt inflated WRITE 132->197 MB, R11)
    float* gO = outW + (size_t)cs * (NBUCKET * ISZ);
    #pragma unroll
    for (int it = 0; it < 8; ++it) {
        int f = tid + it * 256;
        float4 w4 = wreg[it];
        int bl = blv[it];
        float4 r = w4;
        if (bl >= 0) {
            float coef = diff_l[bl];
            float4 l4  = lreg[it];
            r.x = fminf(fmaxf(w4.x - coef * l4.x, -WCLIP), WCLIP);
            r.y = fminf(fmaxf(w4.y - coef * l4.y, -WCLIP), WCLIP);
            r.z = fminf(fmaxf(w4.z - coef * l4.z, -WCLIP), WCLIP);
            r.w = fminf(fmaxf(w4.w - coef * l4.w, -WCLIP), WCLIP);
        }
        ((float4*)gO)[f] = r;
    }
}

extern "C" void kernel_launch(void* const* d_in, const int* in_sizes, int n_in,
                              void* d_out, int out_size, void* d_ws, size_t ws_size,
                              hipStream_t stream) {
    const float* logits  = (const float*)d_in[0];  // (8,512,64)
    const float* context = (const float*)d_in[1];  // (64,512)
    const float* target  = (const float*)d_in[2];  // (8,64)
    const float* cmaps   = (const float*)d_in[3];  // (8,512,4,512)
    const float* cbias   = (const float*)d_in[4];  // (8,512,4,1)
    const float* weights = (const float*)d_in[5];  // (8,512,16,512)

    float* out  = (float*)d_out;                        // (8,512,64)
    float* outW = out + (size_t)CLASSES * SIZE * BATCH; // (8,512,16,512)

    float* Lt    = (float*)d_ws;            // 1 MB
    float* Lpk   = Lt + 262144;             // 1 MB
    float* ctxT4 = Lpk + 262144;            // 128 KB
    unsigned char* idxb = (unsigned char*)(ctxT4 + 32768);   // 256 KB

    pack_pre<<<72, 256, 0, stream>>>(logits, context, Lt, Lpk, ctxT4);
    dist_kernel<<<CLASSES * SIZE / 4, 256, 0, stream>>>(cmaps, cbias, ctxT4, idxb);
    gln_bc<<<CLASSES * SIZE, 256, 0, stream>>>(target, weights, idxb, Lt, Lpk, out, outW);
}